// Round 4
// baseline (293.106 us; speedup 1.0000x reference)
//
#include <hip/hip_runtime.h>
#include <stdint.h>

#define NVOX 40000
#define CCH  128
#define K2   9
#define NH   5
#define TILES 313

typedef __attribute__((ext_vector_type(8))) short bf16x8;
typedef __attribute__((ext_vector_type(4))) float f32x4;

__device__ __forceinline__ unsigned short f2b(float f) {
  union { float f; unsigned int u; } v; v.f = f;
  return (unsigned short)((v.u + 0x7fffu + ((v.u >> 16) & 1u)) >> 16);
}
__device__ __forceinline__ float b2f(unsigned short u) {
  union { unsigned int u; float f; } v; v.u = ((unsigned int)u) << 16;
  return v.f;
}
__device__ __forceinline__ void g2l16(const void* g, void* l) {
  __builtin_amdgcn_global_load_lds(
      (const __attribute__((address_space(1))) unsigned int*)g,
      (__attribute__((address_space(3))) unsigned int*)l, 16, 0, 0);
}
// XOR-swizzled LDS address (shorts) for logical (row, short-col)
__device__ __forceinline__ int swz(int row, int col) {
  return row * 128 + ((((col >> 3) ^ (row & 15)) << 3) | (col & 7));
}

// ---- fused prep: feats fp32->bf16 (blocks 0..4999), W1 cvt+transpose (5000..5179) ----
__global__ void prep(const float4* __restrict__ feats, ushort4* __restrict__ fb,
                     const float* __restrict__ w1, unsigned short* __restrict__ w1t) {
  __shared__ unsigned short t[128 * 34];
  int b = blockIdx.x;
  if (b < 5000) {
    int i = b * 256 + threadIdx.x;
    if (i < NVOX * CCH / 4) {
      float4 v = feats[i];
      ushort4 r;
      r.x = f2b(v.x); r.y = f2b(v.y); r.z = f2b(v.z); r.w = f2b(v.w);
      fb[i] = r;
    }
    return;
  }
  int bb = b - 5000;           // 0..179
  int tile = bb >> 2;          // h*9+k, 0..44
  int q = bb & 3;              // c-quarter
  const float* src = w1 + (size_t)tile * 16384 + q * 32 * 128;
  for (int e = threadIdx.x; e < 4096; e += 256) {
    int c = e >> 7, d = e & 127;
    t[d * 34 + c] = f2b(src[e]);
  }
  __syncthreads();
  unsigned short* dst = w1t + (size_t)tile * 16384 + q * 32;
  for (int e = threadIdx.x; e < 4096; e += 256) {
    int d = e >> 5, c = e & 31;
    dst[d * 128 + c] = t[d * 34 + c];
  }
}

// stage one 128x128 bf16 B tile into LDS (swizzled), 8 g2l16 per wave
__device__ __forceinline__ void stageB(unsigned short* dstbuf, const unsigned short* wp,
                                       int wave, int lane) {
  int lcol = lane & 15, lrow = lane >> 4;
#pragma unroll
  for (int i = 0; i < 8; ++i) {
    int elem = wave * 4096 + i * 512;
    int row = (elem >> 7) + lrow;
    g2l16(wp + row * 128 + ((lcol ^ (row & 15)) << 3), &dstbuf[elem]);
  }
}

// ---- gather-GEMM: A fragments loaded DIRECTLY from global (no LDS, no barrier),
// B double-buffered in LDS; exactly one barrier per tap, with the B(k+1) stage
// in flight across the whole tap-k compute phase. ----
__global__ void __launch_bounds__(256, 2) conv_gemm(
    const unsigned short* __restrict__ fb,   // feats bf16 [N][128]
    const int* __restrict__ nbr,             // [N][9]
    const unsigned short* __restrict__ w1t,  // [H][9][d=128][c=128] bf16
    unsigned short* __restrict__ yb,         // [H][N][128] bf16
    float* __restrict__ sums)                // [2][H][128]
{
  __shared__ unsigned short Bs[2][128 * 128];
  __shared__ int idxs[128 * K2];

  const int bid = blockIdx.x;
  const int s = bid / 40;
  const int r = bid % 40;
  const int h = r >> 3;        // 0..4
  const int x = r & 7;         // xcd lane
  const int tile = s * 8 + x;
  if (tile >= TILES) return;
  const int n0 = tile * 128;

  const int tid = threadIdx.x;
  const int wave = tid >> 6;
  const int lane = tid & 63;
  const int m = lane & 15;     // fragment row/col within 16
  const int quad = lane >> 4;  // 0..3
  const int wm = wave >> 1, wn = wave & 1;

  for (int i = tid; i < 128 * K2; i += 256) {
    int rr = i / K2;
    int kk = i - rr * K2;
    int gn = n0 + rr; if (gn > NVOX - 1) gn = NVOX - 1;
    idxs[i] = nbr[gn * K2 + kk];
  }

  // stage B(0) into Bs[0]
  stageB(Bs[0], w1t + (((size_t)h * K2 + 0) << 14), wave, lane);
  __syncthreads();  // idxs ready (B(0) drain happens at loop-top barrier)

  f32x4 acc[4][4] = {};

  for (int k = 0; k < K2; ++k) {
    // drain: B(k) g2l16s were issued one full tap ago -> ~free wait
    asm volatile("s_waitcnt vmcnt(0)" ::: "memory");
    __syncthreads();

    // kick off B(k+1) into the other buffer; stays in flight all tap
    if (k + 1 < K2)
      stageB(Bs[(k + 1) & 1], w1t + (((size_t)h * K2 + k + 1) << 14), wave, lane);

    const unsigned short* Bcur = Bs[k & 1];

    // A row pointers for this tap (per-lane gather, direct to VGPR frags)
    const unsigned short* aptr[4];
#pragma unroll
    for (int mi = 0; mi < 4; ++mi) {
      int rowA = idxs[(wm * 64 + mi * 16 + m) * K2 + k];
      aptr[mi] = fb + (size_t)rowA * CCH + quad * 8;
    }

#pragma unroll
    for (int kc = 0; kc < 4; ++kc) {
      bf16x8 af[4], bfr[4];
#pragma unroll
      for (int mi = 0; mi < 4; ++mi)
        af[mi] = *(const bf16x8*)(aptr[mi] + kc * 32);
#pragma unroll
      for (int ni = 0; ni < 4; ++ni) {
        int row = wn * 64 + ni * 16 + m;
        bfr[ni] = *(const bf16x8*)&Bcur[row * CCH + (((kc * 4 + quad) ^ (row & 15)) << 3)];
      }
#pragma unroll
      for (int mi = 0; mi < 4; ++mi)
#pragma unroll
        for (int ni = 0; ni < 4; ++ni)
          acc[mi][ni] = __builtin_amdgcn_mfma_f32_16x16x32_bf16(af[mi], bfr[ni], acc[mi][ni], 0, 0, 0);
    }
  }

  // epilogue into Bs[1] (tap 8 read Bs[0]; Bs[1] is free, own-quadrant writes
  // need no barrier first)
  unsigned short* epi = Bs[1];
#pragma unroll
  for (int mi = 0; mi < 4; ++mi)
#pragma unroll
    for (int ni = 0; ni < 4; ++ni)
#pragma unroll
      for (int rr = 0; rr < 4; ++rr) {
        int row = wm * 64 + mi * 16 + quad * 4 + rr;
        int col = wn * 64 + ni * 16 + m;
        epi[swz(row, col)] = f2b(acc[mi][ni][rr]);
      }
  __syncthreads();

  // coalesced y store (un-swizzle on read)
  for (int i = tid; i < 2048; i += 256) {
    int row = i >> 4;
    int c = i & 15;
    if (n0 + row < NVOX)
      *(bf16x8*)(yb + ((size_t)h * NVOX + n0 + row) * CCH + c * 8) =
          *(const bf16x8*)&epi[row * 128 + ((c ^ (row & 15)) << 3)];
  }

  // BN partial stats
  {
    int col = tid & 127, half = tid >> 7;
    int rbase = half * 64;
    int nvalid = NVOX - n0 - rbase;
    if (nvalid > 64) nvalid = 64;
    float sm = 0.f, q = 0.f;
    for (int rr = 0; rr < nvalid; ++rr) {
      float z = b2f(epi[swz(rbase + rr, col)]);
      sm += z; q += z * z;
    }
    if (nvalid > 0) {
      atomicAdd(&sums[h * CCH + col], sm);
      atomicAdd(&sums[NH * CCH + h * CCH + col], q);
    }
  }
}

// ---- finalize BN ----
__global__ void finalize_bn(const float* __restrict__ sums, const float* __restrict__ gamma,
                            const float* __restrict__ beta, float* __restrict__ ssb) {
  int h = blockIdx.x, c = threadIdx.x;
  float mean = sums[h * CCH + c] * (1.f / NVOX);
  float var = sums[NH * CCH + h * CCH + c] * (1.f / NVOX) - mean * mean;
  float rstd = rsqrtf(var + 1e-5f);
  float scale = rstd * gamma[h * CCH + c];
  ssb[h * CCH + c] = scale;
  ssb[NH * CCH + h * CCH + c] = beta[h * CCH + c] - mean * scale;
}

// ---- BN + ReLU + 1x1 heads: 64 voxels/block, LDS-staged coalesced reads,
// d-split over 4 waves, register partials + one LDS reduction ----
__global__ void __launch_bounds__(256) head_fuse(
    const unsigned short* __restrict__ yb, const float* __restrict__ ssb,
    const float* __restrict__ w_hm, const float* __restrict__ b_hm,
    const float* __restrict__ w_ce, const float* __restrict__ b_ce,
    const float* __restrict__ w_cz, const float* __restrict__ b_cz,
    const float* __restrict__ w_dm, const float* __restrict__ b_dm,
    const float* __restrict__ w_rt, const float* __restrict__ b_rt,
    float* __restrict__ out)
{
  __shared__ unsigned short t[64 * 128];   // 16 KB, swizzled
  __shared__ float pbuf[4][64][12];        // 12.3 KB

  const int tid = threadIdx.x;
  const int v0 = blockIdx.x * 64;          // 625 blocks exactly cover 40000
  const int vx = tid & 63;
  const int qd = tid >> 6;                 // wave-uniform d-quarter

  float part[11];
#pragma unroll
  for (int j = 0; j < 11; ++j) part[j] = 0.f;

#pragma unroll
  for (int h = 0; h < NH; ++h) {
    __syncthreads();  // buffer free (prev head consumed)
    // stage 64 rows coalesced: 16 threads per row, 256B contiguous per group
#pragma unroll
    for (int i = 0; i < 4; ++i) {
      int idx = i * 256 + tid;
      int row = idx >> 4, c = idx & 15;
      *(bf16x8*)&t[row * 128 + ((c ^ (row & 15)) << 3)] =
          *(const bf16x8*)(yb + ((size_t)h * NVOX + v0 + row) * CCH + c * 8);
    }
    __syncthreads();

    const float* sc = ssb + h * CCH;
    const float* sh = ssb + NH * CCH + h * CCH;
    const float* wp; int oc, off;
    switch (h) {
      case 0: wp = w_hm; oc = 3; off = 0; break;
      case 1: wp = w_ce; oc = 2; off = 3; break;
      case 2: wp = w_cz; oc = 1; off = 5; break;
      case 3: wp = w_dm; oc = 3; off = 6; break;
      default: wp = w_rt; oc = 2; off = 9; break;
    }
#pragma unroll
    for (int qq = 0; qq < 4; ++qq) {
      int q8 = qd * 4 + qq;
      bf16x8 pk = *(const bf16x8*)&t[vx * 128 + ((q8 ^ (vx & 15)) << 3)];
#pragma unroll
      for (int e = 0; e < 8; ++e) {
        int d = q8 * 8 + e;
        float z = fmaf(b2f((unsigned short)pk[e]), sc[d], sh[d]);
        z = fmaxf(z, 0.f);
        const float* wr = wp + d * oc;
        part[off] = fmaf(z, wr[0], part[off]);
        if (oc > 1) part[off + 1] = fmaf(z, wr[1], part[off + 1]);
        if (oc > 2) part[off + 2] = fmaf(z, wr[2], part[off + 2]);
      }
    }
  }

  // reduce 4 d-quarters
#pragma unroll
  for (int j = 0; j < 11; ++j) pbuf[qd][vx][j] = part[j];
  __syncthreads();
  if (tid < 64) {
    float o[11];
#pragma unroll
    for (int j = 0; j < 11; ++j)
      o[j] = pbuf[0][tid][j] + pbuf[1][tid][j] + pbuf[2][tid][j] + pbuf[3][tid][j];
    o[0] += b_hm[0]; o[1] += b_hm[1]; o[2] += b_hm[2];
    o[3] += b_ce[0]; o[4] += b_ce[1];
    o[5] += b_cz[0];
    o[6] += b_dm[0]; o[7] += b_dm[1]; o[8] += b_dm[2];
    o[9] += b_rt[0]; o[10] += b_rt[1];
    float* op = out + (size_t)(v0 + tid) * 11;
#pragma unroll
    for (int j = 0; j < 11; ++j) op[j] = o[j];
  }
}

extern "C" void kernel_launch(void* const* d_in, const int* in_sizes, int n_in,
                              void* d_out, int out_size, void* d_ws, size_t ws_size,
                              hipStream_t stream) {
  const float* feats = (const float*)d_in[0];
  const int*   nbr   = (const int*)d_in[1];
  const float* W1    = (const float*)d_in[2];
  const float* gamma = (const float*)d_in[3];
  const float* beta  = (const float*)d_in[4];
  const float* w_hm = (const float*)d_in[5];  const float* b_hm = (const float*)d_in[6];
  const float* w_ce = (const float*)d_in[7];  const float* b_ce = (const float*)d_in[8];
  const float* w_cz = (const float*)d_in[9];  const float* b_cz = (const float*)d_in[10];
  const float* w_dm = (const float*)d_in[11]; const float* b_dm = (const float*)d_in[12];
  const float* w_rt = (const float*)d_in[13]; const float* b_rt = (const float*)d_in[14];
  float* out = (float*)d_out;

  char* ws = (char*)d_ws;
  unsigned short* w1t = (unsigned short*)ws;                   // 11,796,480 B
  unsigned short* fb  = (unsigned short*)(ws + 11796480);      // 10,240,000 B
  unsigned short* yb  = (unsigned short*)(ws + 22036480);      // 51,200,000 B
  float* sums = (float*)(ws + 73236480);                       // 5,120 B
  float* ssb  = (float*)(ws + 73241600);                       // 5,120 B

  hipMemsetAsync(sums, 0, 2 * NH * CCH * sizeof(float), stream);
  prep<<<5180, 256, 0, stream>>>((const float4*)feats, (ushort4*)fb, W1, w1t);
  conv_gemm<<<1600, 256, 0, stream>>>(fb, nbr, w1t, yb, sums);
  finalize_bn<<<NH, CCH, 0, stream>>>(sums, gamma, beta, ssb);
  head_fuse<<<625, 256, 0, stream>>>(yb, ssb, w_hm, b_hm, w_ce, b_ce, w_cz, b_cz,
                                     w_dm, b_dm, w_rt, b_rt, out);
}

// Round 5
// 277.691 us; speedup vs baseline: 1.0555x; 1.0555x over previous
//
#include <hip/hip_runtime.h>
#include <stdint.h>

#define NVOX 40000
#define CCH  128
#define K2   9
#define NH   5
#define TILES 313

typedef __attribute__((ext_vector_type(8))) short bf16x8;
typedef __attribute__((ext_vector_type(4))) float f32x4;

__device__ __forceinline__ unsigned short f2b(float f) {
  union { float f; unsigned int u; } v; v.f = f;
  return (unsigned short)((v.u + 0x7fffu + ((v.u >> 16) & 1u)) >> 16);
}
__device__ __forceinline__ float b2f(unsigned short u) {
  union { unsigned int u; float f; } v; v.u = ((unsigned int)u) << 16;
  return v.f;
}
__device__ __forceinline__ void g2l16(const void* g, void* l) {
  __builtin_amdgcn_global_load_lds(
      (const __attribute__((address_space(1))) unsigned int*)g,
      (__attribute__((address_space(3))) unsigned int*)l, 16, 0, 0);
}
// XOR-swizzled LDS address (shorts) for logical (row, short-col)
__device__ __forceinline__ int swz(int row, int col) {
  return row * 128 + ((((col >> 3) ^ (row & 15)) << 3) | (col & 7));
}

// ---- fused prep: feats fp32->bf16 | W1 cvt+transpose | sums zero ----
__global__ void prep(const float4* __restrict__ feats, ushort4* __restrict__ fb,
                     const float* __restrict__ w1, unsigned short* __restrict__ w1t,
                     float* __restrict__ sums) {
  __shared__ unsigned short t[128 * 34];
  int b = blockIdx.x;
  if (b < 5000) {
    int i = b * 256 + threadIdx.x;
    if (i < NVOX * CCH / 4) {
      float4 v = feats[i];
      ushort4 r;
      r.x = f2b(v.x); r.y = f2b(v.y); r.z = f2b(v.z); r.w = f2b(v.w);
      fb[i] = r;
    }
    return;
  }
  if (b == 5180) {  // zero BN partial sums (ws is poisoned each call)
    for (int i = threadIdx.x; i < 2 * NH * CCH; i += 256) sums[i] = 0.f;
    return;
  }
  int bb = b - 5000;           // 0..179
  int tile = bb >> 2;          // h*9+k, 0..44
  int q = bb & 3;              // c-quarter
  const float* src = w1 + (size_t)tile * 16384 + q * 32 * 128;
  for (int e = threadIdx.x; e < 4096; e += 256) {
    int c = e >> 7, d = e & 127;
    t[d * 34 + c] = f2b(src[e]);
  }
  __syncthreads();
  unsigned short* dst = w1t + (size_t)tile * 16384 + q * 32;
  for (int e = threadIdx.x; e < 4096; e += 256) {
    int d = e >> 5, c = e & 31;
    dst[d * 128 + c] = t[d * 34 + c];
  }
}

// stage one 128x128 bf16 B tile into LDS (swizzled), 8 g2l16 per wave
__device__ __forceinline__ void stageB(unsigned short* dstbuf, const unsigned short* wp,
                                       int wave, int lane) {
  int lcol = lane & 15, lrow = lane >> 4;
#pragma unroll
  for (int i = 0; i < 8; ++i) {
    int elem = wave * 4096 + i * 512;
    int row = (elem >> 7) + lrow;
    g2l16(wp + row * 128 + ((lcol ^ (row & 15)) << 3), &dstbuf[elem]);
  }
}

// stage one 128-row gathered A tile into LDS (swizzled), 8 g2l16 per wave
__device__ __forceinline__ void stageA(unsigned short* dstbuf, const unsigned short* fb,
                                       const int* idxs, int k, int wave, int lane) {
  int lcol = lane & 15, lrow = lane >> 4;
  int ridx[8];
#pragma unroll
  for (int i = 0; i < 8; ++i)
    ridx[i] = idxs[(wave * 32 + i * 4 + lrow) * K2 + k];
#pragma unroll
  for (int i = 0; i < 8; ++i) {
    int row = wave * 32 + i * 4 + lrow;
    g2l16(fb + (size_t)ridx[i] * CCH + ((lcol ^ (row & 15)) << 3),
          &dstbuf[(wave * 32 + i * 4) * CCH]);
  }
}

// ---- gather-GEMM, fully double-buffered: A(k+1)/B(k+1) staged into opposite
// LDS buffers immediately after the tap-(k-1) barrier, in flight across all of
// tap k's MFMAs; one vmcnt(0)+barrier per tap (~free). 1 block/CU. ----
__global__ void __launch_bounds__(256, 1) conv_gemm(
    const unsigned short* __restrict__ fb,   // feats bf16 [N][128]
    const int* __restrict__ nbr,             // [N][9]
    const unsigned short* __restrict__ w1t,  // [H][9][d=128][c=128] bf16
    unsigned short* __restrict__ yb,         // [H][N][128] bf16
    float* __restrict__ sums)                // [2][H][128]
{
  __shared__ __align__(16) unsigned short Asb[2][128 * 128];
  __shared__ __align__(16) unsigned short Bsb[2][128 * 128];
  __shared__ int idxs[128 * K2];

  const int bid = blockIdx.x;
  const int s = bid / 40;
  const int r = bid % 40;
  const int h = r >> 3;        // 0..4
  const int x = r & 7;         // xcd lane
  const int tile = s * 8 + x;
  if (tile >= TILES) return;
  const int n0 = tile * 128;

  const int tid = threadIdx.x;
  const int wave = tid >> 6;
  const int lane = tid & 63;
  const int lcol = lane & 15;  // 0..15
  const int lrow = lane >> 4;  // 0..3
  const int wm = wave >> 1, wn = wave & 1;

  // B(0) has no idx dependency: issue first
  stageB(Bsb[0], w1t + (((size_t)h * K2) << 14), wave, lane);

  for (int i = tid; i < 128 * K2; i += 256) {
    int rr = i / K2;
    int gn = n0 + rr; if (gn > NVOX - 1) gn = NVOX - 1;
    idxs[i] = nbr[gn * K2 + (i - rr * K2)];
  }
  __syncthreads();                      // idxs visible
  stageA(Asb[0], fb, idxs, 0, wave, lane);
  asm volatile("s_waitcnt vmcnt(0)" ::: "memory");
  __syncthreads();                      // A(0), B(0) ready

  f32x4 acc[4][4] = {};

  for (int k = 0; k < K2; ++k) {
    const int buf = k & 1;
    if (k + 1 < K2) {                   // prefetch next tap into free buffers
      stageA(Asb[buf ^ 1], fb, idxs, k + 1, wave, lane);
      stageB(Bsb[buf ^ 1], w1t + (((size_t)h * K2 + k + 1) << 14), wave, lane);
    }
    const unsigned short* Acur = Asb[buf];
    const unsigned short* Bcur = Bsb[buf];

#pragma unroll
    for (int kc = 0; kc < 4; ++kc) {
      bf16x8 af[4], bfr[4];
#pragma unroll
      for (int mi = 0; mi < 4; ++mi) {
        int row = wm * 64 + mi * 16 + lcol;
        af[mi] = *(const bf16x8*)&Acur[row * CCH + (((kc * 4 + lrow) ^ (row & 15)) << 3)];
      }
#pragma unroll
      for (int ni = 0; ni < 4; ++ni) {
        int row = wn * 64 + ni * 16 + lcol;
        bfr[ni] = *(const bf16x8*)&Bcur[row * CCH + (((kc * 4 + lrow) ^ (row & 15)) << 3)];
      }
#pragma unroll
      for (int mi = 0; mi < 4; ++mi)
#pragma unroll
        for (int ni = 0; ni < 4; ++ni)
          acc[mi][ni] = __builtin_amdgcn_mfma_f32_16x16x32_bf16(af[mi], bfr[ni], acc[mi][ni], 0, 0, 0);
    }

    if (k + 1 < K2) {
      asm volatile("s_waitcnt vmcnt(0)" ::: "memory");  // next-tap stage landed
      __syncthreads();
    }
  }

  // ---- epilogue: tap 8 used buf 0, so Asb[1]/Bsb[1] are free ----
  const bool full = (n0 + 128 <= NVOX);

  // y -> Asb[1] (bf16, swizzled); C/D layout: col=lane&15, row=(lane>>4)*4+reg
  unsigned short* epi = Asb[1];
#pragma unroll
  for (int mi = 0; mi < 4; ++mi)
#pragma unroll
    for (int ni = 0; ni < 4; ++ni)
#pragma unroll
      for (int rr = 0; rr < 4; ++rr) {
        int row = wm * 64 + mi * 16 + lrow * 4 + rr;
        int col = wn * 64 + ni * 16 + lcol;
        epi[swz(row, col)] = f2b(acc[mi][ni][rr]);
      }

  // BN partial stats straight from acc (fp32): per-lane covers 16 rows of
  // 4 columns (ni); reduce 8 contributors (wm*4+quad) per column via LDS.
  float2* pb = (float2*)Bsb[1];         // [128 cols][9 pad] float2
#pragma unroll
  for (int ni = 0; ni < 4; ++ni) {
    float sm = 0.f, q = 0.f;
#pragma unroll
    for (int mi = 0; mi < 4; ++mi)
#pragma unroll
      for (int rr = 0; rr < 4; ++rr) {
        float v = acc[mi][ni][rr];
        if (!full && n0 + wm * 64 + mi * 16 + lrow * 4 + rr >= NVOX) v = 0.f;
        sm += v; q += v * v;
      }
    pb[(wn * 64 + ni * 16 + lcol) * 9 + wm * 4 + lrow] = make_float2(sm, q);
  }
  __syncthreads();

  // coalesced y store (un-swizzle on read)
  for (int i = tid; i < 2048; i += 256) {
    int row = i >> 4;
    int c = i & 15;
    if (n0 + row < NVOX)
      *(bf16x8*)(yb + ((size_t)h * NVOX + n0 + row) * CCH + c * 8) =
          *(const bf16x8*)&epi[row * 128 + ((c ^ (row & 15)) << 3)];
  }

  if (tid < 128) {
    float sm = 0.f, q = 0.f;
#pragma unroll
    for (int c = 0; c < 8; ++c) {
      float2 p = pb[tid * 9 + c];
      sm += p.x; q += p.y;
    }
    atomicAdd(&sums[h * CCH + tid], sm);
    atomicAdd(&sums[NH * CCH + h * CCH + tid], q);
  }
}

// ---- finalize BN ----
__global__ void finalize_bn(const float* __restrict__ sums, const float* __restrict__ gamma,
                            const float* __restrict__ beta, float* __restrict__ ssb) {
  int h = blockIdx.x, c = threadIdx.x;
  float mean = sums[h * CCH + c] * (1.f / NVOX);
  float var = sums[NH * CCH + h * CCH + c] * (1.f / NVOX) - mean * mean;
  float rstd = rsqrtf(var + 1e-5f);
  float scale = rstd * gamma[h * CCH + c];
  ssb[h * CCH + c] = scale;
  ssb[NH * CCH + h * CCH + c] = beta[h * CCH + c] - mean * scale;
}

// ---- BN + ReLU + 1x1 heads: 64 voxels/block, LDS-staged coalesced reads,
// d-split over 4 waves, register partials + one LDS reduction ----
__global__ void __launch_bounds__(256) head_fuse(
    const unsigned short* __restrict__ yb, const float* __restrict__ ssb,
    const float* __restrict__ w_hm, const float* __restrict__ b_hm,
    const float* __restrict__ w_ce, const float* __restrict__ b_ce,
    const float* __restrict__ w_cz, const float* __restrict__ b_cz,
    const float* __restrict__ w_dm, const float* __restrict__ b_dm,
    const float* __restrict__ w_rt, const float* __restrict__ b_rt,
    float* __restrict__ out)
{
  __shared__ unsigned short t[64 * 128];   // 16 KB, swizzled
  __shared__ float pbuf[4][64][12];        // 12.3 KB

  const int tid = threadIdx.x;
  const int v0 = blockIdx.x * 64;          // 625 blocks exactly cover 40000
  const int vx = tid & 63;
  const int qd = tid >> 6;                 // wave-uniform d-quarter

  float part[11];
#pragma unroll
  for (int j = 0; j < 11; ++j) part[j] = 0.f;

#pragma unroll
  for (int h = 0; h < NH; ++h) {
    __syncthreads();  // buffer free (prev head consumed)
#pragma unroll
    for (int i = 0; i < 4; ++i) {
      int idx = i * 256 + tid;
      int row = idx >> 4, c = idx & 15;
      *(bf16x8*)&t[row * 128 + ((c ^ (row & 15)) << 3)] =
          *(const bf16x8*)(yb + ((size_t)h * NVOX + v0 + row) * CCH + c * 8);
    }
    __syncthreads();

    const float* sc = ssb + h * CCH;
    const float* sh = ssb + NH * CCH + h * CCH;
    const float* wp; int oc, off;
    switch (h) {
      case 0: wp = w_hm; oc = 3; off = 0; break;
      case 1: wp = w_ce; oc = 2; off = 3; break;
      case 2: wp = w_cz; oc = 1; off = 5; break;
      case 3: wp = w_dm; oc = 3; off = 6; break;
      default: wp = w_rt; oc = 2; off = 9; break;
    }
#pragma unroll
    for (int qq = 0; qq < 4; ++qq) {
      int q8 = qd * 4 + qq;
      bf16x8 pk = *(const bf16x8*)&t[vx * 128 + ((q8 ^ (vx & 15)) << 3)];
#pragma unroll
      for (int e = 0; e < 8; ++e) {
        int d = q8 * 8 + e;
        float z = fmaf(b2f((unsigned short)pk[e]), sc[d], sh[d]);
        z = fmaxf(z, 0.f);
        const float* wr = wp + d * oc;
        part[off] = fmaf(z, wr[0], part[off]);
        if (oc > 1) part[off + 1] = fmaf(z, wr[1], part[off + 1]);
        if (oc > 2) part[off + 2] = fmaf(z, wr[2], part[off + 2]);
      }
    }
  }

#pragma unroll
  for (int j = 0; j < 11; ++j) pbuf[qd][vx][j] = part[j];
  __syncthreads();
  if (tid < 64) {
    float o[11];
#pragma unroll
    for (int j = 0; j < 11; ++j)
      o[j] = pbuf[0][tid][j] + pbuf[1][tid][j] + pbuf[2][tid][j] + pbuf[3][tid][j];
    o[0] += b_hm[0]; o[1] += b_hm[1]; o[2] += b_hm[2];
    o[3] += b_ce[0]; o[4] += b_ce[1];
    o[5] += b_cz[0];
    o[6] += b_dm[0]; o[7] += b_dm[1]; o[8] += b_dm[2];
    o[9] += b_rt[0]; o[10] += b_rt[1];
    float* op = out + (size_t)(v0 + tid) * 11;
#pragma unroll
    for (int j = 0; j < 11; ++j) op[j] = o[j];
  }
}

extern "C" void kernel_launch(void* const* d_in, const int* in_sizes, int n_in,
                              void* d_out, int out_size, void* d_ws, size_t ws_size,
                              hipStream_t stream) {
  const float* feats = (const float*)d_in[0];
  const int*   nbr   = (const int*)d_in[1];
  const float* W1    = (const float*)d_in[2];
  const float* gamma = (const float*)d_in[3];
  const float* beta  = (const float*)d_in[4];
  const float* w_hm = (const float*)d_in[5];  const float* b_hm = (const float*)d_in[6];
  const float* w_ce = (const float*)d_in[7];  const float* b_ce = (const float*)d_in[8];
  const float* w_cz = (const float*)d_in[9];  const float* b_cz = (const float*)d_in[10];
  const float* w_dm = (const float*)d_in[11]; const float* b_dm = (const float*)d_in[12];
  const float* w_rt = (const float*)d_in[13]; const float* b_rt = (const float*)d_in[14];
  float* out = (float*)d_out;

  char* ws = (char*)d_ws;
  unsigned short* w1t = (unsigned short*)ws;                   // 11,796,480 B
  unsigned short* fb  = (unsigned short*)(ws + 11796480);      // 10,240,000 B
  unsigned short* yb  = (unsigned short*)(ws + 22036480);      // 51,200,000 B
  float* sums = (float*)(ws + 73236480);                       // 5,120 B
  float* ssb  = (float*)(ws + 73241600);                       // 5,120 B

  prep<<<5181, 256, 0, stream>>>((const float4*)feats, (ushort4*)fb, W1, w1t, sums);
  conv_gemm<<<1600, 256, 0, stream>>>(fb, nbr, w1t, yb, sums);
  finalize_bn<<<NH, CCH, 0, stream>>>(sums, gamma, beta, ssb);
  head_fuse<<<625, 256, 0, stream>>>(yb, ssb, w_hm, b_hm, w_ce, b_ce, w_cz, b_cz,
                                     w_dm, b_dm, w_rt, b_rt, out);
}

// Round 6
// 237.115 us; speedup vs baseline: 1.2361x; 1.1711x over previous
//
#include <hip/hip_runtime.h>
#include <stdint.h>

#define NVOX 40000
#define CCH  128
#define K2   9
#define NH   5
#define TILES 313   // ceil(40000/128)

typedef __attribute__((ext_vector_type(8))) short bf16x8;
typedef __attribute__((ext_vector_type(4))) float f32x4;

__device__ __forceinline__ unsigned short f2b(float f) {
  union { float f; unsigned int u; } v; v.f = f;
  return (unsigned short)((v.u + 0x7fffu + ((v.u >> 16) & 1u)) >> 16);
}
__device__ __forceinline__ float b2f(unsigned short u) {
  union { unsigned int u; float f; } v; v.u = ((unsigned int)u) << 16;
  return v.f;
}
__device__ __forceinline__ void g2l16(const void* g, void* l) {
  __builtin_amdgcn_global_load_lds(
      (const __attribute__((address_space(1))) unsigned int*)g,
      (__attribute__((address_space(3))) unsigned int*)l, 16, 0, 0);
}
// XOR-swizzled LDS address (shorts) for logical (row, short-col)
__device__ __forceinline__ int swz(int row, int col) {
  return row * 128 + ((((col >> 3) ^ (row & 15)) << 3) | (col & 7));
}

// ---- fused prep: feats fp32->bf16 | W1 cvt+transpose | sums zero ----
__global__ void prep(const float4* __restrict__ feats, ushort4* __restrict__ fb,
                     const float* __restrict__ w1, unsigned short* __restrict__ w1t,
                     float* __restrict__ sums) {
  __shared__ unsigned short t[128 * 34];
  int b = blockIdx.x;
  if (b < 5000) {
    int i = b * 256 + threadIdx.x;
    if (i < NVOX * CCH / 4) {
      float4 v = feats[i];
      ushort4 r;
      r.x = f2b(v.x); r.y = f2b(v.y); r.z = f2b(v.z); r.w = f2b(v.w);
      fb[i] = r;
    }
    return;
  }
  if (b == 5180) {  // zero BN partial sums (ws is poisoned each call)
    for (int i = threadIdx.x; i < 2 * NH * CCH; i += 256) sums[i] = 0.f;
    return;
  }
  int bb = b - 5000;           // 0..179
  int tile = bb >> 2;          // h*9+k, 0..44
  int q = bb & 3;              // c-quarter
  const float* src = w1 + (size_t)tile * 16384 + q * 32 * 128;
  for (int e = threadIdx.x; e < 4096; e += 256) {
    int c = e >> 7, d = e & 127;
    t[d * 34 + c] = f2b(src[e]);
  }
  __syncthreads();
  unsigned short* dst = w1t + (size_t)tile * 16384 + q * 32;
  for (int e = threadIdx.x; e < 4096; e += 256) {
    int d = e >> 5, c = e & 31;
    dst[d * 128 + c] = t[d * 34 + c];
  }
}

// stage one 128x128 bf16 B tile into LDS (swizzled), 8 g2l16 per wave
__device__ __forceinline__ void stageB(unsigned short* dstbuf, const unsigned short* wp,
                                       int wave, int lane) {
  int lcol = lane & 15, lrow = lane >> 4;
#pragma unroll
  for (int i = 0; i < 8; ++i) {
    int elem = wave * 4096 + i * 512;
    int row = (elem >> 7) + lrow;
    g2l16(wp + row * 128 + ((lcol ^ (row & 15)) << 3), &dstbuf[elem]);
  }
}

// ---- gather-GEMM v6: A fragments in REGISTERS, prefetched one full tap ahead
// (per-wave private rows -> no barrier for A); B double-buffered in LDS via
// global_load_lds, staged at tap start, consumed next tap; one ~free barrier
// per tap. 2 blocks/CU. Wave layout: wave owns rows [wave*32,wave*32+32),
// all 128 output cols (acc 2mi x 8ni). ----
__global__ void __launch_bounds__(256, 2) conv_gemm(
    const unsigned short* __restrict__ fb,   // feats bf16 [N][128]
    const int* __restrict__ nbr,             // [N][9]
    const unsigned short* __restrict__ w1t,  // [H][9][d=128][c=128] bf16
    unsigned short* __restrict__ yb,         // [H][N][128] bf16
    float* __restrict__ sums)                // [2][H][128]
{
  __shared__ __align__(16) unsigned short Bsb[2][128 * 128];  // 64 KB
  __shared__ int idxs[128 * K2];                              // 4.6 KB

  const int bid = blockIdx.x;
  const int s = bid / 40;
  const int r = bid % 40;
  const int h = r >> 3;        // 0..4
  const int x = r & 7;         // xcd lane
  const int tile = s * 8 + x;
  if (tile >= TILES) return;
  const int n0 = tile * 128;

  const int tid = threadIdx.x;
  const int wave = tid >> 6;
  const int lane = tid & 63;
  const int m = lane & 15;     // position within 16
  const int quad = lane >> 4;  // 0..3

  const unsigned short* wh = w1t + ((size_t)h * K2 << 14);

  // B(0) stage first (no dependencies)
  stageB(Bsb[0], wh, wave, lane);

  for (int i = tid; i < 128 * K2; i += 256) {
    int rr = i / K2;
    int gn = n0 + rr; if (gn > NVOX - 1) gn = NVOX - 1;
    idxs[i] = nbr[gn * K2 + (i - rr * K2)];
  }
  __syncthreads();   // idxs visible; compiler drain also lands B(0)

  // A parity registers: [par][mi][kc], each bf16x8
  bf16x8 A[2][2][4];
  {
    int i0 = idxs[(wave * 32 + m) * K2 + 0];
    int i1 = idxs[(wave * 32 + 16 + m) * K2 + 0];
    const unsigned short* p0 = fb + (size_t)i0 * CCH + quad * 8;
    const unsigned short* p1 = fb + (size_t)i1 * CCH + quad * 8;
#pragma unroll
    for (int kc = 0; kc < 4; ++kc) {
      A[0][0][kc] = *(const bf16x8*)(p0 + kc * 32);
      A[0][1][kc] = *(const bf16x8*)(p1 + kc * 32);
    }
  }

  f32x4 acc[2][8] = {};

#pragma unroll
  for (int k = 0; k < K2; ++k) {
    const int par = k & 1;
    if (k + 1 < K2) {
      // stage B(k+1) into the other buffer: in flight across all of tap k
      stageB(Bsb[par ^ 1], wh + ((size_t)(k + 1) << 14), wave, lane);
      // prefetch A(k+1) into the other parity regs (private, no barrier)
      int i0 = idxs[(wave * 32 + m) * K2 + k + 1];
      int i1 = idxs[(wave * 32 + 16 + m) * K2 + k + 1];
      const unsigned short* p0 = fb + (size_t)i0 * CCH + quad * 8;
      const unsigned short* p1 = fb + (size_t)i1 * CCH + quad * 8;
#pragma unroll
      for (int kc = 0; kc < 4; ++kc) {
        A[par ^ 1][0][kc] = *(const bf16x8*)(p0 + kc * 32);
        A[par ^ 1][1][kc] = *(const bf16x8*)(p1 + kc * 32);
      }
    }
    const unsigned short* Bcur = Bsb[par];
#pragma unroll
    for (int kc = 0; kc < 4; ++kc) {
      bf16x8 bfr[8];
#pragma unroll
      for (int ni = 0; ni < 8; ++ni)   // row = ni*16+m, chunk un-XOR by m
        bfr[ni] = *(const bf16x8*)&Bcur[(ni * 16 + m) * CCH + (((kc * 4 + quad) ^ m) << 3)];
#pragma unroll
      for (int ni = 0; ni < 8; ++ni) {
        acc[0][ni] = __builtin_amdgcn_mfma_f32_16x16x32_bf16(A[par][0][kc], bfr[ni], acc[0][ni], 0, 0, 0);
        acc[1][ni] = __builtin_amdgcn_mfma_f32_16x16x32_bf16(A[par][1][kc], bfr[ni], acc[1][ni], 0, 0, 0);
      }
    }
    if (k + 1 < K2) {
      asm volatile("s_waitcnt vmcnt(0)" ::: "memory");  // B(k+1) landed (full-tap distance)
      __syncthreads();
    }
  }

  // ---- epilogue ----
  __syncthreads();   // all waves done reading Bsb[0] (tap 8)
  const bool full = (n0 + 128 <= NVOX);
  unsigned short* epi = (unsigned short*)Bsb[0];  // 32 KB y-transpose
  float2* pb = (float2*)Bsb[1];                   // [128 cols][17 pad] float2

  // C/D layout: col = lane&15, row = quad*4 + reg
#pragma unroll
  for (int mi = 0; mi < 2; ++mi)
#pragma unroll
    for (int ni = 0; ni < 8; ++ni)
#pragma unroll
      for (int rr = 0; rr < 4; ++rr) {
        int row = wave * 32 + mi * 16 + quad * 4 + rr;
        int col = ni * 16 + m;
        epi[swz(row, col)] = f2b(acc[mi][ni][rr]);
      }

  // BN partials straight from acc (fp32)
#pragma unroll
  for (int ni = 0; ni < 8; ++ni) {
    float sm = 0.f, q = 0.f;
#pragma unroll
    for (int mi = 0; mi < 2; ++mi)
#pragma unroll
      for (int rr = 0; rr < 4; ++rr) {
        float v = acc[mi][ni][rr];
        if (!full && n0 + wave * 32 + mi * 16 + quad * 4 + rr >= NVOX) v = 0.f;
        sm += v; q += v * v;
      }
    pb[(ni * 16 + m) * 17 + wave * 4 + quad] = make_float2(sm, q);
  }
  __syncthreads();

  // coalesced y store (un-swizzle on read)
  for (int i = tid; i < 2048; i += 256) {
    int row = i >> 4;
    int c = i & 15;
    if (n0 + row < NVOX)
      *(bf16x8*)(yb + ((size_t)h * NVOX + n0 + row) * CCH + c * 8) =
          *(const bf16x8*)&epi[row * 128 + ((c ^ (row & 15)) << 3)];
  }

  if (tid < 128) {
    float sm = 0.f, q = 0.f;
#pragma unroll
    for (int c = 0; c < 16; ++c) {
      float2 p = pb[tid * 17 + c];
      sm += p.x; q += p.y;
    }
    atomicAdd(&sums[h * CCH + tid], sm);
    atomicAdd(&sums[NH * CCH + h * CCH + tid], q);
  }
}

// ---- finalize BN ----
__global__ void finalize_bn(const float* __restrict__ sums, const float* __restrict__ gamma,
                            const float* __restrict__ beta, float* __restrict__ ssb) {
  int h = blockIdx.x, c = threadIdx.x;
  float mean = sums[h * CCH + c] * (1.f / NVOX);
  float var = sums[NH * CCH + h * CCH + c] * (1.f / NVOX) - mean * mean;
  float rstd = rsqrtf(var + 1e-5f);
  float scale = rstd * gamma[h * CCH + c];
  ssb[h * CCH + c] = scale;
  ssb[NH * CCH + h * CCH + c] = beta[h * CCH + c] - mean * scale;
}

// ---- BN + ReLU + 1x1 heads: 64 voxels/block, LDS-staged coalesced reads,
// d-split over 4 waves, register partials + one LDS reduction ----
__global__ void __launch_bounds__(256) head_fuse(
    const unsigned short* __restrict__ yb, const float* __restrict__ ssb,
    const float* __restrict__ w_hm, const float* __restrict__ b_hm,
    const float* __restrict__ w_ce, const float* __restrict__ b_ce,
    const float* __restrict__ w_cz, const float* __restrict__ b_cz,
    const float* __restrict__ w_dm, const float* __restrict__ b_dm,
    const float* __restrict__ w_rt, const float* __restrict__ b_rt,
    float* __restrict__ out)
{
  __shared__ unsigned short t[64 * 128];   // 16 KB, swizzled
  __shared__ float pbuf[4][64][12];        // 12.3 KB

  const int tid = threadIdx.x;
  const int v0 = blockIdx.x * 64;          // 625 blocks exactly cover 40000
  const int vx = tid & 63;
  const int qd = tid >> 6;                 // wave-uniform d-quarter

  float part[11];
#pragma unroll
  for (int j = 0; j < 11; ++j) part[j] = 0.f;

#pragma unroll
  for (int h = 0; h < NH; ++h) {
    __syncthreads();  // buffer free (prev head consumed)
#pragma unroll
    for (int i = 0; i < 4; ++i) {
      int idx = i * 256 + tid;
      int row = idx >> 4, c = idx & 15;
      *(bf16x8*)&t[row * 128 + ((c ^ (row & 15)) << 3)] =
          *(const bf16x8*)(yb + ((size_t)h * NVOX + v0 + row) * CCH + c * 8);
    }
    __syncthreads();

    const float* sc = ssb + h * CCH;
    const float* sh = ssb + NH * CCH + h * CCH;
    const float* wp; int oc, off;
    switch (h) {
      case 0: wp = w_hm; oc = 3; off = 0; break;
      case 1: wp = w_ce; oc = 2; off = 3; break;
      case 2: wp = w_cz; oc = 1; off = 5; break;
      case 3: wp = w_dm; oc = 3; off = 6; break;
      default: wp = w_rt; oc = 2; off = 9; break;
    }
#pragma unroll
    for (int qq = 0; qq < 4; ++qq) {
      int q8 = qd * 4 + qq;
      bf16x8 pk = *(const bf16x8*)&t[vx * 128 + ((q8 ^ (vx & 15)) << 3)];
#pragma unroll
      for (int e = 0; e < 8; ++e) {
        int d = q8 * 8 + e;
        float z = fmaf(b2f((unsigned short)pk[e]), sc[d], sh[d]);
        z = fmaxf(z, 0.f);
        const float* wr = wp + d * oc;
        part[off] = fmaf(z, wr[0], part[off]);
        if (oc > 1) part[off + 1] = fmaf(z, wr[1], part[off + 1]);
        if (oc > 2) part[off + 2] = fmaf(z, wr[2], part[off + 2]);
      }
    }
  }

#pragma unroll
  for (int j = 0; j < 11; ++j) pbuf[qd][vx][j] = part[j];
  __syncthreads();
  if (tid < 64) {
    float o[11];
#pragma unroll
    for (int j = 0; j < 11; ++j)
      o[j] = pbuf[0][tid][j] + pbuf[1][tid][j] + pbuf[2][tid][j] + pbuf[3][tid][j];
    o[0] += b_hm[0]; o[1] += b_hm[1]; o[2] += b_hm[2];
    o[3] += b_ce[0]; o[4] += b_ce[1];
    o[5] += b_cz[0];
    o[6] += b_dm[0]; o[7] += b_dm[1]; o[8] += b_dm[2];
    o[9] += b_rt[0]; o[10] += b_rt[1];
    float* op = out + (size_t)(v0 + tid) * 11;
#pragma unroll
    for (int j = 0; j < 11; ++j) op[j] = o[j];
  }
}

extern "C" void kernel_launch(void* const* d_in, const int* in_sizes, int n_in,
                              void* d_out, int out_size, void* d_ws, size_t ws_size,
                              hipStream_t stream) {
  const float* feats = (const float*)d_in[0];
  const int*   nbr   = (const int*)d_in[1];
  const float* W1    = (const float*)d_in[2];
  const float* gamma = (const float*)d_in[3];
  const float* beta  = (const float*)d_in[4];
  const float* w_hm = (const float*)d_in[5];  const float* b_hm = (const float*)d_in[6];
  const float* w_ce = (const float*)d_in[7];  const float* b_ce = (const float*)d_in[8];
  const float* w_cz = (const float*)d_in[9];  const float* b_cz = (const float*)d_in[10];
  const float* w_dm = (const float*)d_in[11]; const float* b_dm = (const float*)d_in[12];
  const float* w_rt = (const float*)d_in[13]; const float* b_rt = (const float*)d_in[14];
  float* out = (float*)d_out;

  char* ws = (char*)d_ws;
  unsigned short* w1t = (unsigned short*)ws;                   // 11,796,480 B
  unsigned short* fb  = (unsigned short*)(ws + 11796480);      // 10,240,000 B
  unsigned short* yb  = (unsigned short*)(ws + 22036480);      // 51,200,000 B
  float* sums = (float*)(ws + 73236480);                       // 5,120 B
  float* ssb  = (float*)(ws + 73241600);                       // 5,120 B

  prep<<<5181, 256, 0, stream>>>((const float4*)feats, (ushort4*)fb, W1, w1t, sums);
  conv_gemm<<<1600, 256, 0, stream>>>(fb, nbr, w1t, yb, sums);
  finalize_bn<<<NH, CCH, 0, stream>>>(sums, gamma, beta, ssb);
  head_fuse<<<625, 256, 0, stream>>>(yb, ssb, w_hm, b_hm, w_ce, b_ce, w_cz, b_cz,
                                     w_dm, b_dm, w_rt, b_rt, out);
}